// Round 2
// baseline (710.799 us; speedup 1.0000x reference)
//
#include <hip/hip_runtime.h>
#include <hip/hip_bf16.h>

namespace {
constexpr int NB = 2, NS = 2048, NH = 16, ND = 128;
constexpr int QB = 64, KB = 64;
constexpr int ROWSTRIDE = NH * ND;  // 2048 floats between consecutive seq positions
constexpr float SCALE_LOG2E = 0.08838834764831843f * 1.4426950408889634f;

constexpr int K_OFF = 0;       // K tile  [64][128] bf16, 256B rows, XOR-swizzled
constexpr int V_OFF = 16384;   // Vt tile [128][64] bf16, 128B rows, XOR-swizzled
constexpr int P_OFF = 32768;   // per-wave P [16][72] bf16 (144B rows, padded)
constexpr int P_WSZ = 2304;
constexpr int SMEM_SZ = P_OFF + 4 * P_WSZ;  // 41984 B
}

typedef __attribute__((ext_vector_type(4))) float f32x4;
typedef __attribute__((ext_vector_type(8))) short bf16x8;
typedef __attribute__((ext_vector_type(2))) unsigned int u32x2;

__device__ __forceinline__ unsigned short f2bf(float f) {
  union { __hip_bfloat16 h; unsigned short u; } cv;
  cv.h = __float2bfloat16(f);
  return cv.u;
}

// broadcast per-row value (rows live in group q>>2, reg q&3) to lanes with q = lane&15
__device__ __forceinline__ float bcast_row(const float v[4], int lane) {
  int q = lane & 15;
  int src = ((q >> 2) << 4) | q;   // a lane inside group q>>2
  float a0 = __shfl(v[0], src, 64);
  float a1 = __shfl(v[1], src, 64);
  float a2 = __shfl(v[2], src, 64);
  float a3 = __shfl(v[3], src, 64);
  int r = q & 3;
  return (r == 0) ? a0 : ((r == 1) ? a1 : ((r == 2) ? a2 : a3));
}

__global__ __launch_bounds__(256)
void fattn_fwd(const float* __restrict__ Q, const float* __restrict__ K,
               const float* __restrict__ V, float* __restrict__ O) {
  __shared__ __align__(16) char smem[SMEM_SZ];

  const int qt = blockIdx.x;
  const int h = blockIdx.y;
  const int b = blockIdx.z;
  const int t = threadIdx.x;
  const int w = t >> 6;       // wave 0..3 -> owns q rows [qt*64+w*16, +16)
  const int lane = t & 63;
  const int g = lane >> 4;    // quad-group
  const int cc = lane & 15;

  const size_t bh = ((size_t)b * NS * NH + h) * (size_t)ND;

  // ---- Q fragments in registers: A[row=cc][d = dc*32 + 8g + i] ----
  bf16x8 qf[4];
  {
    const float* qp = Q + bh + (size_t)(qt * QB + w * 16 + cc) * ROWSTRIDE;
#pragma unroll
    for (int dc = 0; dc < 4; ++dc) {
      f32x4 v0 = *reinterpret_cast<const f32x4*>(qp + dc * 32 + 8 * g);
      f32x4 v1 = *reinterpret_cast<const f32x4*>(qp + dc * 32 + 8 * g + 4);
      bf16x8 f;
      f[0] = (short)f2bf(v0[0]); f[1] = (short)f2bf(v0[1]);
      f[2] = (short)f2bf(v0[2]); f[3] = (short)f2bf(v0[3]);
      f[4] = (short)f2bf(v1[0]); f[5] = (short)f2bf(v1[1]);
      f[6] = (short)f2bf(v1[2]); f[7] = (short)f2bf(v1[3]);
      qf[dc] = f;
    }
  }

  f32x4 oacc[8];  // O^T accumulator: row d = mt*16+4g+reg, col q = cc
#pragma unroll
  for (int i = 0; i < 8; ++i) { oacc[i][0] = 0.f; oacc[i][1] = 0.f; oacc[i][2] = 0.f; oacc[i][3] = 0.f; }
  float m_run[4] = {-1e30f, -1e30f, -1e30f, -1e30f};
  float l_run[4] = {0.f, 0.f, 0.f, 0.f};

  char* Kl = smem + K_OFF;
  char* Vl = smem + V_OFF;
  char* Pl = smem + P_OFF + w * P_WSZ;

  for (int kt = 0; kt <= qt; ++kt) {
    const int kb = kt * KB;

    // ---- stage K tile (row-major bf16, swizzled) and V tile (transposed bf16, swizzled) ----
    for (int jj = 0; jj < 8; ++jj) {
      int idx = jj * 256 + t;        // 0..2047 : 64 rows x 32 float4 chunks
      int r = idx >> 5;
      int c4 = idx & 31;
      const float* kp = K + bh + (size_t)(kb + r) * ROWSTRIDE + c4 * 4;
      const float* vp = V + bh + (size_t)(kb + r) * ROWSTRIDE + c4 * 4;
      f32x4 kv = *reinterpret_cast<const f32x4*>(kp);
      f32x4 vv = *reinterpret_cast<const f32x4*>(vp);
      unsigned int klo = (unsigned int)f2bf(kv[0]) | ((unsigned int)f2bf(kv[1]) << 16);
      unsigned int khi = (unsigned int)f2bf(kv[2]) | ((unsigned int)f2bf(kv[3]) << 16);
      int kbyte = (r * 256 + c4 * 8) ^ ((r & 7) << 4);
      u32x2 kk; kk[0] = klo; kk[1] = khi;
      *reinterpret_cast<u32x2*>(Kl + kbyte) = kk;
#pragma unroll
      for (int j = 0; j < 4; ++j) {
        int col = c4 * 4 + j;  // d index -> Vt row
        int vbyte = (col * 128 + r * 2) ^ ((col & 7) << 4);
        *reinterpret_cast<unsigned short*>(Vl + vbyte) = f2bf(vv[j]);
      }
    }
    __syncthreads();

    // ---- S = Q K^T : acc[nt] rows q=4g+reg, col k = nt*16+cc ----
    f32x4 s[4];
#pragma unroll
    for (int nt = 0; nt < 4; ++nt) { s[nt][0] = 0.f; s[nt][1] = 0.f; s[nt][2] = 0.f; s[nt][3] = 0.f; }
#pragma unroll
    for (int nt = 0; nt < 4; ++nt) {
      int row = nt * 16 + cc;
#pragma unroll
      for (int dc = 0; dc < 4; ++dc) {
        int byte = (row * 256 + dc * 64 + g * 16) ^ ((row & 7) << 4);
        bf16x8 kf = *reinterpret_cast<const bf16x8*>(Kl + byte);
        s[nt] = __builtin_amdgcn_mfma_f32_16x16x32_bf16(qf[dc], kf, s[nt], 0, 0, 0);
      }
    }

    // ---- causal mask on diagonal tile ----
    if (kt == qt) {
#pragma unroll
      for (int nt = 0; nt < 4; ++nt)
#pragma unroll
        for (int r = 0; r < 4; ++r)
          if (nt * 16 + cc > w * 16 + g * 4 + r) s[nt][r] = -1e30f;
    }

    // ---- online softmax (row q = 4g+reg; reduce over 16 lanes of the group) ----
    float tmax[4];
#pragma unroll
    for (int r = 0; r < 4; ++r)
      tmax[r] = fmaxf(fmaxf(s[0][r], s[1][r]), fmaxf(s[2][r], s[3][r]));
#pragma unroll
    for (int off = 1; off < 16; off <<= 1) {
#pragma unroll
      for (int r = 0; r < 4; ++r)
        tmax[r] = fmaxf(tmax[r], __shfl_xor(tmax[r], off, 64));
    }
    float alpha[4];
#pragma unroll
    for (int r = 0; r < 4; ++r) {
      float mn = fmaxf(m_run[r], tmax[r]);
      alpha[r] = exp2f((m_run[r] - mn) * SCALE_LOG2E);
      m_run[r] = mn;
    }
    float p[4][4];
    float psum[4] = {0.f, 0.f, 0.f, 0.f};
#pragma unroll
    for (int nt = 0; nt < 4; ++nt)
#pragma unroll
      for (int r = 0; r < 4; ++r) {
        float pv = exp2f((s[nt][r] - m_run[r]) * SCALE_LOG2E);
        p[nt][r] = pv;
        psum[r] += pv;
      }
#pragma unroll
    for (int r = 0; r < 4; ++r) l_run[r] = l_run[r] * alpha[r] + psum[r];

    // rescale O^T accumulator (needs alpha for q = cc)
    float aq = bcast_row(alpha, lane);
#pragma unroll
    for (int mt = 0; mt < 8; ++mt) {
      oacc[mt][0] *= aq; oacc[mt][1] *= aq; oacc[mt][2] *= aq; oacc[mt][3] *= aq;
    }

    // ---- write P tile (bf16) to wave-private LDS ----
#pragma unroll
    for (int nt = 0; nt < 4; ++nt)
#pragma unroll
      for (int r = 0; r < 4; ++r)
        *reinterpret_cast<unsigned short*>(Pl + (g * 4 + r) * 144 + (nt * 16 + cc) * 2) =
            f2bf(p[nt][r]);

    // wave-local fence: P writes must land before fragment reads (wave-private buffer)
    asm volatile("s_waitcnt lgkmcnt(0)" ::: "memory");
    __builtin_amdgcn_sched_barrier(0);

    // ---- O^T += Vt * P^T ----
#pragma unroll
    for (int kc = 0; kc < 2; ++kc) {
      bf16x8 pf = *reinterpret_cast<const bf16x8*>(Pl + cc * 144 + kc * 64 + g * 16);
#pragma unroll
      for (int mt = 0; mt < 8; ++mt) {
        int d = mt * 16 + cc;
        int byte = (d * 128 + kc * 64 + g * 16) ^ ((d & 7) << 4);
        bf16x8 vf = *reinterpret_cast<const bf16x8*>(Vl + byte);
        oacc[mt] = __builtin_amdgcn_mfma_f32_16x16x32_bf16(vf, pf, oacc[mt], 0, 0, 0);
      }
    }
    __syncthreads();  // protect K/V/P LDS before next stage
  }

  // ---- epilogue: finish row sums, normalize, store ----
#pragma unroll
  for (int off = 1; off < 16; off <<= 1) {
#pragma unroll
    for (int r = 0; r < 4; ++r)
      l_run[r] += __shfl_xor(l_run[r], off, 64);
  }
  float Lq = bcast_row(l_run, lane);
  float inv = 1.0f / Lq;

  float* op = O + bh + (size_t)(qt * QB + w * 16 + cc) * ROWSTRIDE;
#pragma unroll
  for (int mt = 0; mt < 8; ++mt)
#pragma unroll
    for (int r = 0; r < 4; ++r)
      op[mt * 16 + g * 4 + r] = oacc[mt][r] * inv;
}

extern "C" void kernel_launch(void* const* d_in, const int* in_sizes, int n_in,
                              void* d_out, int out_size, void* d_ws, size_t ws_size,
                              hipStream_t stream) {
  const float* Q = (const float*)d_in[0];
  const float* K = (const float*)d_in[1];
  const float* V = (const float*)d_in[2];
  float* O = (float*)d_out;
  dim3 grid(NS / QB, NH, NB);
  fattn_fwd<<<grid, dim3(256), 0, stream>>>(Q, K, V, O);
}

// Round 3
// 266.448 us; speedup vs baseline: 2.6677x; 2.6677x over previous
//
#include <hip/hip_runtime.h>
#include <hip/hip_bf16.h>

namespace {
constexpr int NB = 2, NS = 2048, NH = 16, ND = 128;
constexpr int QB = 64, KB = 64;
constexpr int NQT = NS / QB;            // 32 q-tiles -> 16 balanced pairs
constexpr int ROWSTRIDE = NH * ND;      // 2048 floats between seq positions
constexpr float SCALE_LOG2E = 0.08838834764831843f * 1.4426950408889634f;

constexpr int K_OFF = 0;       // K tile  [64][128] bf16, 256B rows, swz ((r&7)<<4)
constexpr int V_OFF = 16384;   // Vt tile [128 d][64 k] bf16, 128B rows, swz (((d>>1)&7)<<4)
constexpr int P_OFF = 32768;   // per-wave P [16][72] bf16 (144B rows, padded)
constexpr int P_WSZ = 2304;
constexpr int SMEM_SZ = P_OFF + 4 * P_WSZ;  // 41984 B -> 3 blocks/CU LDS-wise
}

typedef __attribute__((ext_vector_type(4))) float f32x4;
typedef __attribute__((ext_vector_type(8))) short bf16x8;
typedef __attribute__((ext_vector_type(2))) unsigned int u32x2;

__device__ __forceinline__ unsigned short f2bf(float f) {
  union { __hip_bfloat16 h; unsigned short u; } cv;
  cv.h = __float2bfloat16(f);
  return cv.u;
}

// broadcast per-row value (rows live in group q>>2, reg q&3) to lanes with q = lane&15
__device__ __forceinline__ float bcast_row(const float v[4], int lane) {
  int q = lane & 15;
  int src = ((q >> 2) << 4) | q;
  float a0 = __shfl(v[0], src, 64);
  float a1 = __shfl(v[1], src, 64);
  float a2 = __shfl(v[2], src, 64);
  float a3 = __shfl(v[3], src, 64);
  int r = q & 3;
  return (r == 0) ? a0 : ((r == 1) ? a1 : ((r == 2) ? a2 : a3));
}

__global__ __launch_bounds__(256)
void fattn_fwd(const float* __restrict__ Q, const float* __restrict__ K,
               const float* __restrict__ V, float* __restrict__ O) {
  __shared__ __align__(16) char smem[SMEM_SZ];

  const int pid = blockIdx.x;   // 0..15 : pair index -> q-tiles {pid, 31-pid}
  const int h = blockIdx.y;
  const int b = blockIdx.z;
  const int t = threadIdx.x;
  const int w = t >> 6;
  const int lane = t & 63;
  const int g = lane >> 4;
  const int cc = lane & 15;

  const size_t bh = ((size_t)b * NS * NH + h) * (size_t)ND;

  char* Kl = smem + K_OFF;
  char* Vl = smem + V_OFF;
  char* Pl = smem + P_OFF + w * P_WSZ;

  for (int half = 0; half < 2; ++half) {
    const int qt = half ? (NQT - 1 - pid) : pid;

    // ---- Q fragments in registers: A[row=cc][d = dc*32 + 8g + i] ----
    bf16x8 qf[4];
    {
      const float* qp = Q + bh + (size_t)(qt * QB + w * 16 + cc) * ROWSTRIDE;
#pragma unroll
      for (int dc = 0; dc < 4; ++dc) {
        f32x4 v0 = *reinterpret_cast<const f32x4*>(qp + dc * 32 + 8 * g);
        f32x4 v1 = *reinterpret_cast<const f32x4*>(qp + dc * 32 + 8 * g + 4);
        bf16x8 f;
        f[0] = (short)f2bf(v0[0]); f[1] = (short)f2bf(v0[1]);
        f[2] = (short)f2bf(v0[2]); f[3] = (short)f2bf(v0[3]);
        f[4] = (short)f2bf(v1[0]); f[5] = (short)f2bf(v1[1]);
        f[6] = (short)f2bf(v1[2]); f[7] = (short)f2bf(v1[3]);
        qf[dc] = f;
      }
    }

    f32x4 oacc[8];  // O^T accumulator: row d = mt*16+4g+reg, col q = cc
#pragma unroll
    for (int i = 0; i < 8; ++i) { oacc[i][0] = 0.f; oacc[i][1] = 0.f; oacc[i][2] = 0.f; oacc[i][3] = 0.f; }
    float m_run[4] = {-1e30f, -1e30f, -1e30f, -1e30f};
    float l_run[4] = {0.f, 0.f, 0.f, 0.f};

    for (int kt = 0; kt <= qt; ++kt) {
      const int kb = kt * KB;

      // ---- stage K tile: row-major bf16 [64][128], 8B writes, full bank spread ----
      {
        f32x4 kreg[8];
#pragma unroll
        for (int jj = 0; jj < 8; ++jj) {
          int idx = jj * 256 + t;
          int r = idx >> 5;
          int c4 = idx & 31;
          kreg[jj] = *reinterpret_cast<const f32x4*>(K + bh + (size_t)(kb + r) * ROWSTRIDE + c4 * 4);
        }
#pragma unroll
        for (int jj = 0; jj < 8; ++jj) {
          int idx = jj * 256 + t;
          int r = idx >> 5;
          int c4 = idx & 31;
          unsigned int klo = (unsigned int)f2bf(kreg[jj][0]) | ((unsigned int)f2bf(kreg[jj][1]) << 16);
          unsigned int khi = (unsigned int)f2bf(kreg[jj][2]) | ((unsigned int)f2bf(kreg[jj][3]) << 16);
          int kbyte = (r * 256 + c4 * 8) ^ ((r & 7) << 4);
          u32x2 kk; kk[0] = klo; kk[1] = khi;
          *reinterpret_cast<u32x2*>(Kl + kbyte) = kk;
        }
      }
      // ---- stage V transposed: thread owns 4x4 blocks, register transpose, b64 writes ----
      {
        f32x4 vreg[2][4];
        const int c4 = t & 31;
#pragma unroll
        for (int it = 0; it < 2; ++it) {
          int r0 = ((t >> 5) + 8 * it) * 4;
          const float* vp = V + bh + (size_t)(kb + r0) * ROWSTRIDE + c4 * 4;
#pragma unroll
          for (int j = 0; j < 4; ++j)
            vreg[it][j] = *reinterpret_cast<const f32x4*>(vp + (size_t)j * ROWSTRIDE);
        }
#pragma unroll
        for (int it = 0; it < 2; ++it) {
          int r0 = ((t >> 5) + 8 * it) * 4;
#pragma unroll
          for (int j = 0; j < 4; ++j) {
            int d = 4 * c4 + j;
            unsigned int lo = (unsigned int)f2bf(vreg[it][0][j]) | ((unsigned int)f2bf(vreg[it][1][j]) << 16);
            unsigned int hi = (unsigned int)f2bf(vreg[it][2][j]) | ((unsigned int)f2bf(vreg[it][3][j]) << 16);
            int vbyte = (d * 128 + r0 * 2) ^ (((d >> 1) & 7) << 4);
            u32x2 pk; pk[0] = lo; pk[1] = hi;
            *reinterpret_cast<u32x2*>(Vl + vbyte) = pk;
          }
        }
      }
      __syncthreads();

      // ---- S = Q K^T ----
      f32x4 s[4];
#pragma unroll
      for (int nt = 0; nt < 4; ++nt) { s[nt][0] = 0.f; s[nt][1] = 0.f; s[nt][2] = 0.f; s[nt][3] = 0.f; }
      __builtin_amdgcn_s_setprio(1);
#pragma unroll
      for (int nt = 0; nt < 4; ++nt) {
        int row = nt * 16 + cc;
#pragma unroll
        for (int dc = 0; dc < 4; ++dc) {
          int byte = (row * 256 + dc * 64 + g * 16) ^ ((row & 7) << 4);
          bf16x8 kf = *reinterpret_cast<const bf16x8*>(Kl + byte);
          s[nt] = __builtin_amdgcn_mfma_f32_16x16x32_bf16(qf[dc], kf, s[nt], 0, 0, 0);
        }
      }
      __builtin_amdgcn_s_setprio(0);

      // ---- causal mask on diagonal tile ----
      if (kt == qt) {
#pragma unroll
        for (int nt = 0; nt < 4; ++nt)
#pragma unroll
          for (int r = 0; r < 4; ++r)
            if (nt * 16 + cc > w * 16 + g * 4 + r) s[nt][r] = -1e30f;
      }

      // ---- online softmax (row q = 4g+reg; reduce across 16 lanes of quad-group) ----
      float tmax[4];
#pragma unroll
      for (int r = 0; r < 4; ++r)
        tmax[r] = fmaxf(fmaxf(s[0][r], s[1][r]), fmaxf(s[2][r], s[3][r]));
#pragma unroll
      for (int off = 1; off < 16; off <<= 1) {
#pragma unroll
        for (int r = 0; r < 4; ++r)
          tmax[r] = fmaxf(tmax[r], __shfl_xor(tmax[r], off, 64));
      }
      float alpha[4];
#pragma unroll
      for (int r = 0; r < 4; ++r) {
        float mn = fmaxf(m_run[r], tmax[r]);
        alpha[r] = exp2f((m_run[r] - mn) * SCALE_LOG2E);
        m_run[r] = mn;
      }
      float p[4][4];
      float psum[4] = {0.f, 0.f, 0.f, 0.f};
#pragma unroll
      for (int nt = 0; nt < 4; ++nt)
#pragma unroll
        for (int r = 0; r < 4; ++r) {
          float pv = exp2f((s[nt][r] - m_run[r]) * SCALE_LOG2E);
          p[nt][r] = pv;
          psum[r] += pv;
        }
#pragma unroll
      for (int r = 0; r < 4; ++r) l_run[r] = l_run[r] * alpha[r] + psum[r];

      float aq = bcast_row(alpha, lane);
#pragma unroll
      for (int mt = 0; mt < 8; ++mt) {
        oacc[mt][0] *= aq; oacc[mt][1] *= aq; oacc[mt][2] *= aq; oacc[mt][3] *= aq;
      }

      // ---- write P tile (bf16) to wave-private LDS ----
#pragma unroll
      for (int nt = 0; nt < 4; ++nt)
#pragma unroll
        for (int r = 0; r < 4; ++r)
          *reinterpret_cast<unsigned short*>(Pl + (g * 4 + r) * 144 + (nt * 16 + cc) * 2) =
              f2bf(p[nt][r]);

      asm volatile("s_waitcnt lgkmcnt(0)" ::: "memory");
      __builtin_amdgcn_sched_barrier(0);

      // ---- O^T += Vt * P^T ----
      __builtin_amdgcn_s_setprio(1);
#pragma unroll
      for (int kc = 0; kc < 2; ++kc) {
        bf16x8 pf = *reinterpret_cast<const bf16x8*>(Pl + cc * 144 + kc * 64 + g * 16);
#pragma unroll
        for (int mt = 0; mt < 8; ++mt) {
          int d = mt * 16 + cc;
          int byte = (d * 128 + kc * 64 + g * 16) ^ (((d >> 1) & 7) << 4);
          bf16x8 vf = *reinterpret_cast<const bf16x8*>(Vl + byte);
          oacc[mt] = __builtin_amdgcn_mfma_f32_16x16x32_bf16(vf, pf, oacc[mt], 0, 0, 0);
        }
      }
      __builtin_amdgcn_s_setprio(0);
      __syncthreads();
    }

    // ---- epilogue: finish row sums, normalize, store ----
#pragma unroll
    for (int off = 1; off < 16; off <<= 1) {
#pragma unroll
      for (int r = 0; r < 4; ++r)
        l_run[r] += __shfl_xor(l_run[r], off, 64);
    }
    float Lq = bcast_row(l_run, lane);
    float inv = 1.0f / Lq;

    float* op = O + bh + (size_t)(qt * QB + w * 16 + cc) * ROWSTRIDE;
#pragma unroll
    for (int mt = 0; mt < 8; ++mt)
#pragma unroll
      for (int r = 0; r < 4; ++r)
        op[mt * 16 + g * 4 + r] = oacc[mt][r] * inv;
  }
}

extern "C" void kernel_launch(void* const* d_in, const int* in_sizes, int n_in,
                              void* d_out, int out_size, void* d_ws, size_t ws_size,
                              hipStream_t stream) {
  const float* Q = (const float*)d_in[0];
  const float* K = (const float*)d_in[1];
  const float* V = (const float*)d_in[2];
  float* O = (float*)d_out;
  dim3 grid(NQT / 2, NH, NB);   // 16 balanced q-tile pairs x 16 heads x 2 batch
  fattn_fwd<<<grid, dim3(256), 0, stream>>>(Q, K, V, O);
}